// Round 1
// 413.344 us; speedup vs baseline: 1.0140x; 1.0140x over previous
//
#include <hip/hip_runtime.h>
#include <stdint.h>

// Problem constants
#define N_ATOM 2048
#define K_TOT  32768        // N_ATOM * 16  (k = b*16 + f)
#define KCH    2048         // k per block (16 K-chunks)
#define BK2    128          // k per pipeline iteration
#define NIT    (KCH / BK2)  // 16

typedef __attribute__((ext_vector_type(8))) short bf16x8;
typedef __attribute__((ext_vector_type(4))) float f32x4;

typedef __attribute__((address_space(3))) uint32_t lds_u32;
typedef __attribute__((address_space(1))) uint32_t gbl_u32;

__device__ __forceinline__ void async_ld16(const void* g, void* l) {
  __builtin_amdgcn_global_load_lds((const gbl_u32*)g, (lds_u32*)l, 16, 0, 0);
}

// f32 -> bf16 round-to-nearest-even (used in gt/bond staging)
__device__ __forceinline__ unsigned short f2bf(float x) {
  union { float f; uint32_t u; } v; v.f = x;
  uint32_t r = v.u + 0x7FFFu + ((v.u >> 16) & 1u);
  return (unsigned short)(r >> 16);
}

// pack two f32 -> bf16x2 (round-to-nearest, ties-down): 2 v_add + 1 v_perm
__device__ __forceinline__ uint32_t pack_bf2(float x, float y) {
  union { float f; uint32_t u; } a, b;
  a.f = x; b.f = y;
  uint32_t au = a.u + 0x7FFFu;
  uint32_t bu = b.u + 0x7FFFu;
  return __builtin_amdgcn_perm(bu, au, 0x07060302u);
}

// ---------------------------------------------------------------------------
// Kernel 1 (merged): blocks 0..255  = G[b][o][f] = sum_d node[b,d]*filters[o,f,d]
//                    blocks 256..383 = bond-term epilogue init of out[a][o]
// Both bodies identical math to the previous k_gt / k_bond; one launch saves a
// serialized launch gap and overlaps the two (69.6 KB LDS -> 2 blocks/CU).
// ---------------------------------------------------------------------------
__global__ __launch_bounds__(256) void k_pre(const float* __restrict__ node,
                                             const float* __restrict__ filt,
                                             const float* __restrict__ bond,
                                             unsigned short* __restrict__ Gt,
                                             float* __restrict__ out) {
  __shared__ unsigned short SM[2 * 128 * 136];  // 69,632 B, overlaid
  const int t   = threadIdx.x;
  const int bid = blockIdx.x;

  if (bid < 256) {
    // ---- GEMM: C[m=b][n=o*16+f] = node(2048x128) @ filters_rows(n,:128)^T ----
    unsigned short* As = SM;              // [m][k] bf16, stride 136
    unsigned short* Bs = SM + 128 * 136;  // [n][k] bf16, stride 136
    const int b0 = (bid & 15) * 128;
    const int n0 = (bid >> 4) * 128;

#pragma unroll
    for (int rep = 0; rep < 16; ++rep) {
      int q = rep * 256 + t;
      int row = q >> 5, c4 = q & 31;
      float4 v = *(const float4*)(node + (size_t)(b0 + row) * 128 + c4 * 4);
      unsigned short* dst = &As[row * 136 + c4 * 4];
      dst[0] = f2bf(v.x); dst[1] = f2bf(v.y); dst[2] = f2bf(v.z); dst[3] = f2bf(v.w);
    }
#pragma unroll
    for (int rep = 0; rep < 32; ++rep) {
      int q = rep * 256 + t;
      int row = q >> 6, c2 = q & 63;
      float2 v = *(const float2*)(filt + (size_t)(n0 + row) * 130 + c2 * 2);
      unsigned short* dst = &Bs[row * 136 + c2 * 2];
      dst[0] = f2bf(v.x); dst[1] = f2bf(v.y);
    }
    __syncthreads();

    const int w = t >> 6, l = t & 63;
    const int lm = l & 15, q4 = l >> 4;

    f32x4 acc[2][8];
#pragma unroll
    for (int ms = 0; ms < 2; ++ms)
#pragma unroll
      for (int ns = 0; ns < 8; ++ns)
        acc[ms][ns] = (f32x4){0.f, 0.f, 0.f, 0.f};

#pragma unroll
    for (int ks = 0; ks < 4; ++ks) {
      int ko = ks * 32 + q4 * 8;
      bf16x8 a[2], b[8];
#pragma unroll
      for (int ms = 0; ms < 2; ++ms) {
        int m = w * 32 + ms * 16 + lm;
        a[ms] = *(const bf16x8*)&As[m * 136 + ko];
      }
#pragma unroll
      for (int ns = 0; ns < 8; ++ns) {
        int n = ns * 16 + lm;
        b[ns] = *(const bf16x8*)&Bs[n * 136 + ko];
      }
#pragma unroll
      for (int ms = 0; ms < 2; ++ms)
#pragma unroll
        for (int ns = 0; ns < 8; ++ns)
          acc[ms][ns] = __builtin_amdgcn_mfma_f32_16x16x32_bf16(a[ms], b[ns], acc[ms][ns], 0, 0, 0);
    }

#pragma unroll
    for (int ms = 0; ms < 2; ++ms)
#pragma unroll
      for (int ns = 0; ns < 8; ++ns)
#pragma unroll
        for (int i = 0; i < 4; ++i) {
          int m = w * 32 + ms * 16 + q4 * 4 + i;
          int n = ns * 16 + lm;
          Gt[(size_t)(b0 + m) * 2048 + n0 + n] = f2bf(acc[ms][ns][i]);
        }
  } else {
    // ---- bond term: out[a][o] = sum_{f,j} bond[a,f,j] * filters[o,f,128+j] ----
    float* fb = (float*)SM;               // [o][f*2+j], 16 KB
    float* bl = (float*)SM + 128 * 32;    // [a_rel][f*2+j], 2 KB
    const int a0 = (bid - 256) * 16;

#pragma unroll
    for (int r = 0; r < 16; ++r) {
      int idx = r * 256 + t;              // 4096 = 128 o * 32
      int o = idx >> 5, fj = idx & 31;
      int f = fj >> 1, j = fj & 1;
      fb[idx] = filt[(size_t)o * 2080 + f * 130 + 128 + j];
    }
    bl[t]       = bond[(size_t)a0 * 32 + t];
    bl[256 + t] = bond[(size_t)a0 * 32 + 256 + t];
    __syncthreads();

#pragma unroll
    for (int r = 0; r < 8; ++r) {
      int idx = r * 256 + t;              // 2048 = 16 a * 128 o
      int aa = idx >> 7, o = idx & 127;
      const float2* bp = (const float2*)&bl[aa * 32];
      const float2* fp = (const float2*)&fb[o * 32];
      float acc = 0.f;
#pragma unroll
      for (int f = 0; f < 16; ++f) {
        float2 b2 = bp[f], f2 = fp[f];
        acc += b2.x * f2.x + b2.y * f2.y;
      }
      out[(size_t)(a0 + aa) * 128 + o] = acc;
    }
  }
}

// ---------------------------------------------------------------------------
// Kernel 2: out[a][o] += conn2d(2048 x 32768) @ G(32768 x 128), split-K=16.
// 512 threads / 8 waves per block; wave owns 16 rows x 128 cols.
//
// Pipeline change vs previous version: the per-iteration barrier no longer
// drains vmcnt(0) (which emptied the whole VMEM pipe — including the per-wave
// conn A-loads — every 6400-cycle HBM period). Now:
//   - A (conn, HBM, 64 KB/CU/iter) is register double-buffered, prefetched
//     TWO iterations ahead, and flies ACROSS the barrier.
//   - B (Gt via global_load_lds, L2/LLC-resident) is staged FIRST each iter
//     (oldest queue position) so a counted s_waitcnt vmcnt(8) drains exactly
//     {B_{i+1}, A_{i+1}} while leaving A_{i+2}'s 8 loads in flight.
// Numerics identical to previous version (same rounding, same accum order).
// ---------------------------------------------------------------------------
__global__ __launch_bounds__(512, 2) void k_main(const float* __restrict__ conn,
                                                 const unsigned short* __restrict__ Gt,
                                                 float* __restrict__ out) {
  __shared__ unsigned short Bh[2][8 * 128 * 16];  // 2 x 32 KB, [b_rel][o][f]

  const int t  = threadIdx.x;
  const int w  = t >> 6, l = t & 63;
  const int lm = l & 15, q4 = l >> 4;
  const int a0 = blockIdx.x * 128;
  const int kc = blockIdx.y * KCH;

  f32x4 acc[8];
#pragma unroll
  for (int ns = 0; ns < 8; ++ns)
    acc[ns] = (f32x4){0.f, 0.f, 0.f, 0.f};

  // this wave's 16 C-rows are w*16 .. w*16+15; lane lm owns row w*16+lm
  const float* arow = conn + (size_t)(a0 + w * 16 + lm) * K_TOT;

  // ---- B async stage: 32 KB contiguous from Gt + k0*128 shorts (4 instr) ----
  auto stageB = [&](int buf, int k0) {
    const char* gB = (const char*)(Gt + (size_t)k0 * 128);
#pragma unroll
    for (int r = 0; r < 4; ++r) {
      const void* g = gB + (size_t)(r * 512 + t) * 16;
      void* lb = (void*)((char*)&Bh[buf][0] + r * 8192 + w * 1024);  // wave-uniform
      async_ld16(g, lb);
    }
  };

  // ---- A register loads, double-buffered: [buf][kk][lo/hi] fp32, nt (8 instr) ----
  f32x4 Ar[2][4][2];
#define LOADA(BUF, K0)                                                      \
  do {                                                                      \
    _Pragma("unroll") for (int kk = 0; kk < 4; ++kk) {                      \
      const float* p = arow + (K0) + kk * 32 + q4 * 8;                      \
      Ar[BUF][kk][0] = __builtin_nontemporal_load((const f32x4*)p);         \
      Ar[BUF][kk][1] = __builtin_nontemporal_load((const f32x4*)(p + 4));   \
    }                                                                       \
  } while (0)

  // prologue: queue = [B0(4), A0(8), A1(8)]; release when B0 staged.
  stageB(0, kc);
  LOADA(0, kc);
  LOADA(1, kc + BK2);
  __builtin_amdgcn_sched_barrier(0);
  asm volatile("s_waitcnt vmcnt(16)" ::: "memory");  // oldest 4 (= B0) done
  __builtin_amdgcn_s_barrier();
  __builtin_amdgcn_sched_barrier(0);

#pragma unroll
  for (int it = 0; it < NIT; ++it) {
    const int cur = it & 1;  // compile-time after full unroll

    // issue next B tile FIRST: it must sit older than A_{it+2} in the queue
    // so the end-of-iter counted wait covers it without draining A_{it+2}.
    if (it + 1 < NIT) stageB(1 - cur, kc + (it + 1) * BK2);

    // convert A_it (compiler auto-inserts the counted vmcnt on Ar[cur] uses)
    bf16x8 af[4];
#pragma unroll
    for (int kk = 0; kk < 4; ++kk) {
      f32x4 lo = Ar[cur][kk][0], hi = Ar[cur][kk][1];
      union { bf16x8 v; uint32_t u[4]; } cvt;
      cvt.u[0] = pack_bf2(lo[0], lo[1]);
      cvt.u[1] = pack_bf2(lo[2], lo[3]);
      cvt.u[2] = pack_bf2(hi[0], hi[1]);
      cvt.u[3] = pack_bf2(hi[2], hi[3]);
      af[kk] = cvt.v;
    }

    // A two iterations ahead into the buffer just freed by the convert
    if (it + 2 < NIT) LOADA(cur, kc + (it + 2) * BK2);

    // compute: 4 K-steps of 16x16x32 over Bh[cur]
#pragma unroll
    for (int kk = 0; kk < 4; ++kk) {
      const int b_rel = 2 * kk + (q4 >> 1);
      const int f0 = (q4 & 1) * 8;
#pragma unroll
      for (int ns = 0; ns < 8; ++ns) {
        int o = ns * 16 + lm;
        bf16x8 b = *(const bf16x8*)&Bh[cur][b_rel * 2048 + o * 16 + f0];
        acc[ns] = __builtin_amdgcn_mfma_f32_16x16x32_bf16(af[kk], b, acc[ns], 0, 0, 0);
      }
    }

    // counted drain + raw barrier: B_{it+1} (and A_{it+1}, needed next convert
    // anyway) complete; A_{it+2}'s 8 loads stay in flight across the barrier.
    if (it + 1 < NIT) {
      __builtin_amdgcn_sched_barrier(0);
      if (it + 2 < NIT) {
        asm volatile("s_waitcnt vmcnt(8)" ::: "memory");
      } else {
        asm volatile("s_waitcnt vmcnt(0)" ::: "memory");  // it==14: no A in flight
      }
      __builtin_amdgcn_s_barrier();
      __builtin_amdgcn_sched_barrier(0);
    }
  }
#undef LOADA

  // epilogue: split-K combine via fp32 atomics (16-lane coalesced segments)
#pragma unroll
  for (int ns = 0; ns < 8; ++ns)
#pragma unroll
    for (int i = 0; i < 4; ++i) {
      int m = w * 16 + q4 * 4 + i;
      int n = ns * 16 + lm;
      atomicAdd(&out[(size_t)(a0 + m) * 128 + n], acc[ns][i]);
    }
}

// ---------------------------------------------------------------------------
extern "C" void kernel_launch(void* const* d_in, const int* in_sizes, int n_in,
                              void* d_out, int out_size, void* d_ws, size_t ws_size,
                              hipStream_t stream) {
  const float* node = (const float*)d_in[0];  // (2048, 128)
  const float* conn = (const float*)d_in[1];  // (2048, 2048, 16)
  const float* bond = (const float*)d_in[2];  // (2048, 16, 2)
  const float* filt = (const float*)d_in[3];  // (128, 16, 130)
  float* out = (float*)d_out;                 // (2048, 128)

  if (ws_size < (size_t)N_ATOM * 2048 * sizeof(unsigned short)) return;  // need 8 MB
  unsigned short* Gt = (unsigned short*)d_ws;  // [b][o][f] bf16, 8 MB

  k_pre <<<dim3(384),    256, 0, stream>>>(node, filt, bond, Gt, out);
  k_main<<<dim3(16, 16), 512, 0, stream>>>(conn, Gt, out);
}

// Round 2
// 407.492 us; speedup vs baseline: 1.0285x; 1.0144x over previous
//
#include <hip/hip_runtime.h>
#include <stdint.h>

// Problem constants
#define N_ATOM 2048
#define K_TOT  32768        // N_ATOM * 16  (k = b*16 + f)
#define KCH    2048         // k per block (16 K-chunks)
#define BK2    128          // k per pipeline iteration
#define NIT    (KCH / BK2)  // 16

typedef __attribute__((ext_vector_type(8))) short bf16x8;
typedef __attribute__((ext_vector_type(4))) float f32x4;

typedef __attribute__((address_space(3))) uint32_t lds_u32;
typedef __attribute__((address_space(1))) uint32_t gbl_u32;

__device__ __forceinline__ void async_ld16(const void* g, void* l) {
  __builtin_amdgcn_global_load_lds((const gbl_u32*)g, (lds_u32*)l, 16, 0, 0);
}

// f32 -> bf16 round-to-nearest-even (used in gt/bond staging)
__device__ __forceinline__ unsigned short f2bf(float x) {
  union { float f; uint32_t u; } v; v.f = x;
  uint32_t r = v.u + 0x7FFFu + ((v.u >> 16) & 1u);
  return (unsigned short)(r >> 16);
}

// pack two f32 -> bf16x2 (round-to-nearest, ties-down): 2 v_add + 1 v_perm
__device__ __forceinline__ uint32_t pack_bf2(float x, float y) {
  union { float f; uint32_t u; } a, b;
  a.f = x; b.f = y;
  uint32_t au = a.u + 0x7FFFu;
  uint32_t bu = b.u + 0x7FFFu;
  return __builtin_amdgcn_perm(bu, au, 0x07060302u);
}

// ---------------------------------------------------------------------------
// Kernel 1 (merged): blocks 0..255  = G[b][o][f] = sum_d node[b,d]*filters[o,f,d]
//                    blocks 256..383 = bond-term epilogue init of out[a][o]
// ---------------------------------------------------------------------------
__global__ __launch_bounds__(256) void k_pre(const float* __restrict__ node,
                                             const float* __restrict__ filt,
                                             const float* __restrict__ bond,
                                             unsigned short* __restrict__ Gt,
                                             float* __restrict__ out) {
  __shared__ unsigned short SM[2 * 128 * 136];  // 69,632 B, overlaid
  const int t   = threadIdx.x;
  const int bid = blockIdx.x;

  if (bid < 256) {
    // ---- GEMM: C[m=b][n=o*16+f] = node(2048x128) @ filters_rows(n,:128)^T ----
    unsigned short* As = SM;              // [m][k] bf16, stride 136
    unsigned short* Bs = SM + 128 * 136;  // [n][k] bf16, stride 136
    const int b0 = (bid & 15) * 128;
    const int n0 = (bid >> 4) * 128;

#pragma unroll
    for (int rep = 0; rep < 16; ++rep) {
      int q = rep * 256 + t;
      int row = q >> 5, c4 = q & 31;
      float4 v = *(const float4*)(node + (size_t)(b0 + row) * 128 + c4 * 4);
      unsigned short* dst = &As[row * 136 + c4 * 4];
      dst[0] = f2bf(v.x); dst[1] = f2bf(v.y); dst[2] = f2bf(v.z); dst[3] = f2bf(v.w);
    }
#pragma unroll
    for (int rep = 0; rep < 32; ++rep) {
      int q = rep * 256 + t;
      int row = q >> 6, c2 = q & 63;
      float2 v = *(const float2*)(filt + (size_t)(n0 + row) * 130 + c2 * 2);
      unsigned short* dst = &Bs[row * 136 + c2 * 2];
      dst[0] = f2bf(v.x); dst[1] = f2bf(v.y);
    }
    __syncthreads();

    const int w = t >> 6, l = t & 63;
    const int lm = l & 15, q4 = l >> 4;

    f32x4 acc[2][8];
#pragma unroll
    for (int ms = 0; ms < 2; ++ms)
#pragma unroll
      for (int ns = 0; ns < 8; ++ns)
        acc[ms][ns] = (f32x4){0.f, 0.f, 0.f, 0.f};

#pragma unroll
    for (int ks = 0; ks < 4; ++ks) {
      int ko = ks * 32 + q4 * 8;
      bf16x8 a[2], b[8];
#pragma unroll
      for (int ms = 0; ms < 2; ++ms) {
        int m = w * 32 + ms * 16 + lm;
        a[ms] = *(const bf16x8*)&As[m * 136 + ko];
      }
#pragma unroll
      for (int ns = 0; ns < 8; ++ns) {
        int n = ns * 16 + lm;
        b[ns] = *(const bf16x8*)&Bs[n * 136 + ko];
      }
#pragma unroll
      for (int ms = 0; ms < 2; ++ms)
#pragma unroll
        for (int ns = 0; ns < 8; ++ns)
          acc[ms][ns] = __builtin_amdgcn_mfma_f32_16x16x32_bf16(a[ms], b[ns], acc[ms][ns], 0, 0, 0);
    }

#pragma unroll
    for (int ms = 0; ms < 2; ++ms)
#pragma unroll
      for (int ns = 0; ns < 8; ++ns)
#pragma unroll
        for (int i = 0; i < 4; ++i) {
          int m = w * 32 + ms * 16 + q4 * 4 + i;
          int n = ns * 16 + lm;
          Gt[(size_t)(b0 + m) * 2048 + n0 + n] = f2bf(acc[ms][ns][i]);
        }
  } else {
    // ---- bond term: out[a][o] = sum_{f,j} bond[a,f,j] * filters[o,f,128+j] ----
    float* fb = (float*)SM;               // [o][f*2+j], 16 KB
    float* bl = (float*)SM + 128 * 32;    // [a_rel][f*2+j], 2 KB
    const int a0 = (bid - 256) * 16;

#pragma unroll
    for (int r = 0; r < 16; ++r) {
      int idx = r * 256 + t;              // 4096 = 128 o * 32
      int o = idx >> 5, fj = idx & 31;
      int f = fj >> 1, j = fj & 1;
      fb[idx] = filt[(size_t)o * 2080 + f * 130 + 128 + j];
    }
    bl[t]       = bond[(size_t)a0 * 32 + t];
    bl[256 + t] = bond[(size_t)a0 * 32 + 256 + t];
    __syncthreads();

#pragma unroll
    for (int r = 0; r < 8; ++r) {
      int idx = r * 256 + t;              // 2048 = 16 a * 128 o
      int aa = idx >> 7, o = idx & 127;
      const float2* bp = (const float2*)&bl[aa * 32];
      const float2* fp = (const float2*)&fb[o * 32];
      float acc = 0.f;
#pragma unroll
      for (int f = 0; f < 16; ++f) {
        float2 b2 = bp[f], f2 = fp[f];
        acc += b2.x * f2.x + b2.y * f2.y;
      }
      out[(size_t)(a0 + aa) * 128 + o] = acc;
    }
  }
}

// ---------------------------------------------------------------------------
// Kernel 2: out[a][o] += conn2d(2048 x 32768) @ G(32768 x 128), split-K=16.
//
// Restructured vs previous version: 256 threads / 4 waves per block, 64 rows
// per block, grid (32,16) = 512 blocks -> TWO independent blocks per CU
// (LDS 64 KB x 2 = 128 KB <= 160). Same waves/SIMD as before, but the two
// blocks barrier independently: when one block sits at its s_barrier, the
// other block's waves keep HBM fed. Previous layout (1 block/CU, 8 waves on
// one barrier) idled the whole CU's memory pipe at every iteration boundary.
//
// Pipeline (unchanged semantics):
//   - A (conn, HBM) register double-buffered, prefetched 2 iters ahead,
//     flies ACROSS the barrier (counted vmcnt, never 0 mid-loop).
//   - B (Gt, L2-resident) staged via global_load_lds FIRST each iter so the
//     end-of-iter s_waitcnt vmcnt(8) drains exactly {B_{i+1}, A_{i+1}} while
//     A_{i+2}'s 8 loads stay in flight.
// Numerics identical (same rounding, same per-wave accumulation order).
// ---------------------------------------------------------------------------
__global__ __launch_bounds__(256, 2) void k_main(const float* __restrict__ conn,
                                                 const unsigned short* __restrict__ Gt,
                                                 float* __restrict__ out) {
  __shared__ unsigned short Bh[2][8 * 128 * 16];  // 2 x 32 KB, [b_rel][o][f]

  const int t  = threadIdx.x;
  const int w  = t >> 6, l = t & 63;      // w in 0..3
  const int lm = l & 15, q4 = l >> 4;
  const int a0 = blockIdx.x * 64;         // 64 rows per block
  const int kc = blockIdx.y * KCH;

  f32x4 acc[8];
#pragma unroll
  for (int ns = 0; ns < 8; ++ns)
    acc[ns] = (f32x4){0.f, 0.f, 0.f, 0.f};

  // this wave's 16 C-rows are w*16 .. w*16+15; lane lm owns row w*16+lm
  const float* arow = conn + (size_t)(a0 + w * 16 + lm) * K_TOT;

  // ---- B async stage: 32 KB contiguous from Gt + k0*128 shorts (8 instr) ----
  auto stageB = [&](int buf, int k0) {
    const char* gB = (const char*)(Gt + (size_t)k0 * 128);
#pragma unroll
    for (int r = 0; r < 8; ++r) {
      const void* g = gB + (size_t)(r * 256 + t) * 16;
      void* lb = (void*)((char*)&Bh[buf][0] + r * 4096 + w * 1024);  // wave-uniform
      async_ld16(g, lb);
    }
  };

  // ---- A register loads, double-buffered: [buf][kk][lo/hi] fp32, nt (8 instr) ----
  f32x4 Ar[2][4][2];
#define LOADA(BUF, K0)                                                      \
  do {                                                                      \
    _Pragma("unroll") for (int kk = 0; kk < 4; ++kk) {                      \
      const float* p = arow + (K0) + kk * 32 + q4 * 8;                      \
      Ar[BUF][kk][0] = __builtin_nontemporal_load((const f32x4*)p);         \
      Ar[BUF][kk][1] = __builtin_nontemporal_load((const f32x4*)(p + 4));   \
    }                                                                       \
  } while (0)

  // prologue: queue = [B0(8), A0(8), A1(8)]; release when B0 staged.
  stageB(0, kc);
  LOADA(0, kc);
  LOADA(1, kc + BK2);
  __builtin_amdgcn_sched_barrier(0);
  asm volatile("s_waitcnt vmcnt(16)" ::: "memory");  // oldest 8 (= B0) done
  __builtin_amdgcn_s_barrier();
  __builtin_amdgcn_sched_barrier(0);

#pragma unroll
  for (int it = 0; it < NIT; ++it) {
    const int cur = it & 1;  // compile-time after full unroll

    // issue next B tile FIRST: it must sit older than A_{it+2} in the queue
    // so the end-of-iter counted wait covers it without draining A_{it+2}.
    if (it + 1 < NIT) stageB(1 - cur, kc + (it + 1) * BK2);

    // convert A_it (compiler auto-inserts the counted vmcnt on Ar[cur] uses)
    bf16x8 af[4];
#pragma unroll
    for (int kk = 0; kk < 4; ++kk) {
      f32x4 lo = Ar[cur][kk][0], hi = Ar[cur][kk][1];
      union { bf16x8 v; uint32_t u[4]; } cvt;
      cvt.u[0] = pack_bf2(lo[0], lo[1]);
      cvt.u[1] = pack_bf2(lo[2], lo[3]);
      cvt.u[2] = pack_bf2(hi[0], hi[1]);
      cvt.u[3] = pack_bf2(hi[2], hi[3]);
      af[kk] = cvt.v;
    }

    // A two iterations ahead into the buffer just freed by the convert
    if (it + 2 < NIT) LOADA(cur, kc + (it + 2) * BK2);

    // compute: 4 K-steps of 16x16x32 over Bh[cur]
#pragma unroll
    for (int kk = 0; kk < 4; ++kk) {
      const int b_rel = 2 * kk + (q4 >> 1);
      const int f0 = (q4 & 1) * 8;
#pragma unroll
      for (int ns = 0; ns < 8; ++ns) {
        int o = ns * 16 + lm;
        bf16x8 b = *(const bf16x8*)&Bh[cur][b_rel * 2048 + o * 16 + f0];
        acc[ns] = __builtin_amdgcn_mfma_f32_16x16x32_bf16(af[kk], b, acc[ns], 0, 0, 0);
      }
    }

    // counted drain + raw barrier: B_{it+1} (and A_{it+1}, needed next convert
    // anyway) complete; A_{it+2}'s 8 loads stay in flight across the barrier.
    if (it + 1 < NIT) {
      __builtin_amdgcn_sched_barrier(0);
      if (it + 2 < NIT) {
        asm volatile("s_waitcnt vmcnt(8)" ::: "memory");
      } else {
        asm volatile("s_waitcnt vmcnt(0)" ::: "memory");  // it==14: no A in flight
      }
      __builtin_amdgcn_s_barrier();
      __builtin_amdgcn_sched_barrier(0);
    }
  }
#undef LOADA

  // epilogue: split-K combine via fp32 atomics (16-lane coalesced segments)
#pragma unroll
  for (int ns = 0; ns < 8; ++ns)
#pragma unroll
    for (int i = 0; i < 4; ++i) {
      int m = w * 16 + q4 * 4 + i;
      int n = ns * 16 + lm;
      atomicAdd(&out[(size_t)(a0 + m) * 128 + n], acc[ns][i]);
    }
}

// ---------------------------------------------------------------------------
extern "C" void kernel_launch(void* const* d_in, const int* in_sizes, int n_in,
                              void* d_out, int out_size, void* d_ws, size_t ws_size,
                              hipStream_t stream) {
  const float* node = (const float*)d_in[0];  // (2048, 128)
  const float* conn = (const float*)d_in[1];  // (2048, 2048, 16)
  const float* bond = (const float*)d_in[2];  // (2048, 16, 2)
  const float* filt = (const float*)d_in[3];  // (128, 16, 130)
  float* out = (float*)d_out;                 // (2048, 128)

  if (ws_size < (size_t)N_ATOM * 2048 * sizeof(unsigned short)) return;  // need 8 MB
  unsigned short* Gt = (unsigned short*)d_ws;  // [b][o][f] bf16, 8 MB

  k_pre <<<dim3(384),    256, 0, stream>>>(node, filt, bond, Gt, out);
  k_main<<<dim3(32, 16), 256, 0, stream>>>(conn, Gt, out);
}